// Round 6
// baseline (116.394 us; speedup 1.0000x reference)
//
#include <hip/hip_runtime.h>
#include <cfloat>

#define LAT_ROWS 32768
#define DIM 512
#define KCODES 1024

// ---- geometry: 4 blocks/CU ----
constexpr int BM = 32;             // latent rows per block
constexpr int BN = 128;            // codes per code-tile
constexpr int BK = 64;             // d-chunk
constexpr int NTM = 256;           // main threads (4 waves = 4 code-groups)
constexpr int NTP = 512;           // prep threads
constexpr int NCT = KCODES / BN;   // 8
constexpr int NDK = DIM / BK;      // 8
constexpr int TT = NCT * NDK;      // 64
constexpr int CUNITS = BN * BK / 8;   // 1024 16B-units per CB tile

// workspace layout (bytes)
constexpr size_t WS_LSUM = 0;                      // 64 doubles
constexpr size_t WS_NORM = 512;                    // 1024 f32
constexpr size_t WS_CBBF = 4608;                   // 1 MB bf16 (swizzled tiles)
constexpr size_t WS_XBF  = 1053696;                // 32 MB bf16 (fragment-linear)
constexpr size_t WS_NEEDED = WS_XBF + (size_t)LAT_ROWS * DIM * 2;  // 34,608,128

typedef short bf16x8 __attribute__((ext_vector_type(8)));
typedef float f32x4 __attribute__((ext_vector_type(4)));
typedef unsigned short u16;
typedef u16 u16x8 __attribute__((ext_vector_type(8)));

__device__ __forceinline__ u16 f2bf(float f) {  // round-to-nearest-even
  unsigned u = __float_as_uint(f);
  u += 0x7FFF + ((u >> 16) & 1);
  return (u16)(u >> 16);
}

#define GLOAD_LDS(g, l)                                     \
  __builtin_amdgcn_global_load_lds(                         \
      (const __attribute__((address_space(1))) void*)(g),   \
      (__attribute__((address_space(3))) void*)(l), 16, 0, 0)

// ------------- prep: X->bf16 fragment-linear + sum(x^2); CB->bf16 tiles; norms -------------
// Xbf unit index: (((b*8+dk)*2+nf)*2+ks)*64 + lane
// content: row r = b*32+nf*16+(lane&15), dims d0 = dk*64+ks*32+(lane>>4)*8 (8 bf16)
__global__ void __launch_bounds__(NTP)
vq_prep(const float* __restrict__ X, const float* __restrict__ CB,
        u16* __restrict__ Xbf, u16* __restrict__ CBbf,
        float* __restrict__ norms, double* __restrict__ lsum) {
  __shared__ float sp[8];
  const int bb = blockIdx.x;
  const int tid = threadIdx.x;
  if (bb < 4096) {  // ---- X convert
    const int id = bb * NTP + tid;         // 0 .. 2^21-1
    const int l15 = id & 15;
    const int l4 = (id >> 4) & 3;
    const int ks = (id >> 6) & 1;
    const int nf = (id >> 7) & 1;
    const int dk = (id >> 8) & 7;
    const int b = id >> 11;
    const int r = b * 32 + nf * 16 + l15;
    const int d0 = dk * 64 + ks * 32 + l4 * 8;
    const float* src = X + (size_t)r * DIM + d0;
    const float4 a = *(const float4*)src;
    const float4 c = *(const float4*)(src + 4);
    float s = a.x * a.x + a.y * a.y + a.z * a.z + a.w * a.w +
              c.x * c.x + c.y * c.y + c.z * c.z + c.w * c.w;
    u16x8 v;
    v[0] = f2bf(a.x); v[1] = f2bf(a.y); v[2] = f2bf(a.z); v[3] = f2bf(a.w);
    v[4] = f2bf(c.x); v[5] = f2bf(c.y); v[6] = f2bf(c.z); v[7] = f2bf(c.w);
    *(u16x8*)(Xbf + (size_t)id * 8) = v;
#pragma unroll
    for (int m = 1; m < 64; m <<= 1) s += __shfl_xor(s, m, 64);
    const int lane = tid & 63, w = tid >> 6;
    if (lane == 0) sp[w] = s;
    __syncthreads();
    if (tid == 0) {
      double t = 0.0;
      for (int i = 0; i < 8; ++i) t += (double)sp[i];
      atomicAdd(&lsum[bb & 63], t);
    }
  } else if (bb < 4224) {  // ---- CB convert: swizzled tile unit (ct,dk), BN=128
    const int id = (bb - 4096) * NTP + tid;  // 0 .. 65535
    const int ct = id >> 13;                 // 8 ct tiles
    const int dk = (id >> 10) & 7;
    const int u = id & 1023;
    const int r = u >> 3, qp = u & 7, q = qp ^ (r & 7);
    const float* src = CB + ((size_t)ct * BN + r) * DIM + dk * BK + q * 8;
    const float4 a = *(const float4*)src;
    const float4 c = *(const float4*)(src + 4);
    u16x8 v;
    v[0] = f2bf(a.x); v[1] = f2bf(a.y); v[2] = f2bf(a.z); v[3] = f2bf(a.w);
    v[4] = f2bf(c.x); v[5] = f2bf(c.y); v[6] = f2bf(c.z); v[7] = f2bf(c.w);
    *(u16x8*)(CBbf + (size_t)id * 8) = v;
  } else {  // ---- norms (f32 exact): one wave per code
    const int gw = (bb - 4224) * 8 + (tid >> 6);
    const int l = tid & 63;
    const float4 a = *(const float4*)&CB[(size_t)gw * DIM + l * 8];
    const float4 b = *(const float4*)&CB[(size_t)gw * DIM + l * 8 + 4];
    float s = a.x * a.x + a.y * a.y + a.z * a.z + a.w * a.w +
              b.x * b.x + b.y * b.y + b.z * b.z + b.w * b.w;
#pragma unroll
    for (int m = 1; m < 64; m <<= 1) s += __shfl_xor(s, m, 64);
    if (l == 0) norms[gw] = s;
  }
}

// ------- main: small blocks (4/CU), CB dbuf in LDS, X direct from global -------
__global__ void __launch_bounds__(NTM, 4)
vq_main7(const u16* __restrict__ Xbf, const u16* __restrict__ CBbf,
         const float* __restrict__ CB, const float* __restrict__ norms,
         float* __restrict__ outq, double* __restrict__ lsum) {
  __shared__ u16 Cs[2][CUNITS * 8];   // 16 KB x2
  __shared__ float snorm[KCODES];     // 4 KB
  __shared__ float redm[BM][4];
  __shared__ int redi[BM][4];
  __shared__ int idxs[BM];
  __shared__ float wpart[4];

  const int tid = threadIdx.x;
  const int lane = tid & 63;
  const int l15 = lane & 15;
  const int l4 = lane >> 4;
  const int wm = tid >> 6;       // code group (32 codes per wave)
  const int row0 = blockIdx.x * BM;

  for (int i = tid; i < KCODES; i += NTM) snorm[i] = norms[i];

  // per-wave X fragment base (fragment-linear; one coalesced 16B/lane load per frag)
  const u16* xw = Xbf + ((size_t)blockIdx.x * 2048 + lane) * 8;

  auto stage = [&](int b, int t) {   // 4 gload_lds per thread (CB tile only)
    const int ct = t >> 3, dk = t & 7;
    const u16* cp = CBbf + (size_t)(ct * NDK + dk) * CUNITS * 8;
#pragma unroll
    for (int k = 0; k < 4; ++k) {
      const int u = tid + k * NTM;
      GLOAD_LDS(cp + (size_t)u * 8, &Cs[b][u * 8]);
    }
  };

  f32x4 acc[2][2];                 // [mf codes][nf rows]
  float rmin[2]; int ridx[2];
#pragma unroll
  for (int i = 0; i < 2; ++i) { rmin[i] = FLT_MAX; ridx[i] = 0; }

  stage(0, 0);
  __syncthreads();

  for (int t = 0; t < TT; ++t) {
    const int dk = t & 7;
    const int cur = t & 1;
    // X fragments first (older in vmcnt order than the stage prefetch)
    bf16x8 bfr[2][2];   // [ks][nf]
    const u16* xp = xw + (size_t)(dk * 256) * 8;
#pragma unroll
    for (int ks = 0; ks < 2; ++ks)
#pragma unroll
      for (int nf = 0; nf < 2; ++nf)
        bfr[ks][nf] = *(const bf16x8*)(xp + (size_t)(nf * 128 + ks * 64) * 8);
    if (t + 1 < TT) stage(cur ^ 1, t + 1);   // prefetch stays in flight past bfr waits

    if (dk == 0) {
      const f32x4 z = {0.f, 0.f, 0.f, 0.f};
#pragma unroll
      for (int mf = 0; mf < 2; ++mf)
#pragma unroll
        for (int nf = 0; nf < 2; ++nf) acc[mf][nf] = z;
    }
#pragma unroll
    for (int ks = 0; ks < 2; ++ks) {
      bf16x8 af[2];
#pragma unroll
      for (int mf = 0; mf < 2; ++mf) {
        const int r = wm * 32 + mf * 16 + l15;
        const int ph = (ks * 4 + l4) ^ (r & 7);
        af[mf] = *(const bf16x8*)&Cs[cur][(r * 8 + ph) * 8];
      }
      __builtin_amdgcn_s_setprio(1);
#pragma unroll
      for (int mf = 0; mf < 2; ++mf)
#pragma unroll
        for (int nf = 0; nf < 2; ++nf)
          acc[mf][nf] = __builtin_amdgcn_mfma_f32_16x16x32_bf16(
              af[mf], bfr[ks][nf], acc[mf][nf], 0, 0, 0);
      __builtin_amdgcn_s_setprio(0);
    }
    if (dk == NDK - 1) {  // fold finished code-tile into running argmin
      const int ct = t >> 3;
#pragma unroll
      for (int mf = 0; mf < 2; ++mf) {
#pragma unroll
        for (int r = 0; r < 4; ++r) {
          const int code = ct * BN + wm * 32 + mf * 16 + l4 * 4 + r;
          const float cn = snorm[code];
#pragma unroll
          for (int nf = 0; nf < 2; ++nf) {
            const float s = fmaf(-2.f, acc[mf][nf][r], cn);
            if (s < rmin[nf]) { rmin[nf] = s; ridx[nf] = code; }
          }
        }
      }
    }
    __syncthreads();   // buffer swap; 3 co-resident blocks hide the drain
  }

  // cross-lane argmin (lanes l15, +16, +32, +48 share a row; tie -> lowest idx)
#pragma unroll
  for (int m = 16; m <= 32; m <<= 1) {
#pragma unroll
    for (int nf = 0; nf < 2; ++nf) {
      const float om = __shfl_xor(rmin[nf], m, 64);
      const int oi = __shfl_xor(ridx[nf], m, 64);
      if (om < rmin[nf] || (om == rmin[nf] && oi < ridx[nf])) {
        rmin[nf] = om; ridx[nf] = oi;
      }
    }
  }
  if (l4 == 0) {
#pragma unroll
    for (int nf = 0; nf < 2; ++nf) {
      const int row = nf * 16 + l15;
      redm[row][wm] = rmin[nf];
      redi[row][wm] = ridx[nf];
    }
  }
  __syncthreads();

  float tot = 0.f;
  if (tid < BM) {   // cross-wave reduce (4 code-group waves per row)
    float bm = redm[tid][0]; int bi = redi[tid][0];
#pragma unroll
    for (int c = 1; c < 4; ++c) {
      const float m_ = redm[tid][c]; const int i_ = redi[tid][c];
      if (m_ < bm || (m_ == bm && i_ < bi)) { bm = m_; bi = i_; }
    }
    idxs[tid] = bi;
    tot = bm;       // min(||c||^2 - 2 x.c); sum(x^2) added by prep pass
  }
#pragma unroll
  for (int m = 1; m < 64; m <<= 1) tot += __shfl_xor(tot, m, 64);
  if (lane == 0) wpart[tid >> 6] = tot;
  __syncthreads();
  if (tid == 0) {
    double s = 0.0;
    for (int i = 0; i < 4; ++i) s += (double)wpart[i];
    atomicAdd(&lsum[blockIdx.x & 63], s);
  }

  // gather + write quantized (exact f32 codebook rows, CB is L2-hot)
  for (int g = tid; g < BM * (DIM / 4); g += NTM) {
    const int row = g >> 7;
    const int d4 = (g & 127) * 4;
    const int idx = idxs[row];
    *(float4*)&outq[(size_t)(row0 + row) * DIM + d4] =
        *(const float4*)&CB[(size_t)idx * DIM + d4];
  }
}

// ------------- fallback (round-2 path, small workspace; own constants) -------------
constexpr int FBM = 128, FBN = 256, FBK = 64, FNT = 512, FNDK = 8, FTT = 32;

__global__ void __launch_bounds__(FNT, 2)
vq_main_fb(const float* __restrict__ X, const float* __restrict__ CB,
           const float* __restrict__ norms, float* __restrict__ outq,
           double* __restrict__ lsum) {
  __shared__ u16 Xs[2][FBM * FBK];
  __shared__ u16 Cs[2][FBN * FBK];
  __shared__ float snorm[KCODES];
  __shared__ float redm[FBM][4];
  __shared__ int redi[FBM][4];
  __shared__ int idxs[FBM];
  __shared__ float wpart[8];

  const int tid = threadIdx.x;
  const int lane = tid & 63;
  const int l15 = lane & 15;
  const int l4 = lane >> 4;
  const int wid = tid >> 6;
  const int wm = wid & 3;
  const int wn = wid >> 2;
  const int row0 = blockIdx.x * FBM;

  for (int i = tid; i < KCODES; i += FNT) snorm[i] = norms[i];

  int xlds[2]; const float* xbase[2];
#pragma unroll
  for (int k = 0; k < 2; ++k) {
    const int u = tid + k * FNT;
    const int r = u >> 3, q = u & 7, ph = q ^ (r & 7);
    xlds[k] = r * FBK + ph * 8;
    xbase[k] = X + (size_t)(row0 + r) * DIM + q * 8;
  }
  int clds[4]; const float* cbase[4];
#pragma unroll
  for (int k = 0; k < 4; ++k) {
    const int u = tid + k * FNT;
    const int r = u >> 3, q = u & 7, ph = q ^ (r & 7);
    clds[k] = r * FBK + ph * 8;
    cbase[k] = CB + (size_t)r * DIM + q * 8;
  }

  f32x4 acc[4][4];
  float rmin[4]; int ridx[4];
#pragma unroll
  for (int i = 0; i < 4; ++i) { rmin[i] = FLT_MAX; ridx[i] = 0; }
  float sq = 0.f;

  float4 lx[2][2], lc[4][2];
  auto load_tile = [&](int tn) {
    const int ct = tn >> 3, dk = tn & 7;
    const int xo = dk * FBK;
    const size_t co = (size_t)ct * FBN * DIM + dk * FBK;
#pragma unroll
    for (int k = 0; k < 2; ++k) {
      lx[k][0] = *(const float4*)(xbase[k] + xo);
      lx[k][1] = *(const float4*)(xbase[k] + xo + 4);
    }
#pragma unroll
    for (int k = 0; k < 4; ++k) {
      lc[k][0] = *(const float4*)(cbase[k] + co);
      lc[k][1] = *(const float4*)(cbase[k] + co + 4);
    }
  };
  auto write_tile = [&](int b, bool acc_sq) {
#pragma unroll
    for (int k = 0; k < 2; ++k) {
      u16x8 v;
      const float* f = (const float*)&lx[k][0];
#pragma unroll
      for (int j = 0; j < 8; ++j) {
        const float x = f[j];
        if (acc_sq) sq = fmaf(x, x, sq);
        v[j] = f2bf(x);
      }
      *(u16x8*)&Xs[b][xlds[k]] = v;
    }
#pragma unroll
    for (int k = 0; k < 4; ++k) {
      u16x8 v;
      const float* f = (const float*)&lc[k][0];
#pragma unroll
      for (int j = 0; j < 8; ++j) v[j] = f2bf(f[j]);
      *(u16x8*)&Cs[b][clds[k]] = v;
    }
  };

  load_tile(0);
  write_tile(0, true);
  __syncthreads();

  int cur = 0;
  for (int t = 0; t < FTT; ++t) {
    const int dk = t & 7;
    const bool pre = (t + 1 < FTT);
    if (pre) load_tile(t + 1);
    if (dk == 0) {
      const f32x4 z = {0.f, 0.f, 0.f, 0.f};
#pragma unroll
      for (int mf = 0; mf < 4; ++mf)
#pragma unroll
        for (int nf = 0; nf < 4; ++nf) acc[mf][nf] = z;
    }
    const u16* xb = Xs[cur];
    const u16* cb = Cs[cur];
#pragma unroll
    for (int ks = 0; ks < 2; ++ks) {
      bf16x8 af[4], bfr[4];
#pragma unroll
      for (int mf = 0; mf < 4; ++mf) {
        const int r = wm * 64 + mf * 16 + l15;
        const int ph = (ks * 4 + l4) ^ (r & 7);
        af[mf] = *(const bf16x8*)&cb[r * FBK + ph * 8];
      }
#pragma unroll
      for (int nf = 0; nf < 4; ++nf) {
        const int r = wn * 64 + nf * 16 + l15;
        const int ph = (ks * 4 + l4) ^ (r & 7);
        bfr[nf] = *(const bf16x8*)&xb[r * FBK + ph * 8];
      }
#pragma unroll
      for (int mf = 0; mf < 4; ++mf)
#pragma unroll
        for (int nf = 0; nf < 4; ++nf)
          acc[mf][nf] = __builtin_amdgcn_mfma_f32_16x16x32_bf16(
              af[mf], bfr[nf], acc[mf][nf], 0, 0, 0);
    }
    if (dk == FNDK - 1) {
      const int ct = t >> 3;
#pragma unroll
      for (int mf = 0; mf < 4; ++mf) {
#pragma unroll
        for (int r = 0; r < 4; ++r) {
          const int code = ct * FBN + wm * 64 + mf * 16 + l4 * 4 + r;
          const float cn = snorm[code];
#pragma unroll
          for (int nf = 0; nf < 4; ++nf) {
            const float s = fmaf(-2.f, acc[mf][nf][r], cn);
            if (s < rmin[nf]) { rmin[nf] = s; ridx[nf] = code; }
          }
        }
      }
    }
    if (pre) write_tile(cur ^ 1, (t + 1) < FNDK);
    __syncthreads();
    cur ^= 1;
  }

#pragma unroll
  for (int m = 16; m <= 32; m <<= 1) {
#pragma unroll
    for (int nf = 0; nf < 4; ++nf) {
      const float om = __shfl_xor(rmin[nf], m, 64);
      const int oi = __shfl_xor(ridx[nf], m, 64);
      if (om < rmin[nf] || (om == rmin[nf] && oi < ridx[nf])) {
        rmin[nf] = om; ridx[nf] = oi;
      }
    }
  }
  if (l4 == 0) {
#pragma unroll
    for (int nf = 0; nf < 4; ++nf) {
      const int row = wn * 64 + nf * 16 + l15;
      redm[row][wm] = rmin[nf];
      redi[row][wm] = ridx[nf];
    }
  }
  __syncthreads();

  float tot = sq;
  if (tid < FBM) {
    float bm = redm[tid][0]; int bi = redi[tid][0];
#pragma unroll
    for (int c = 1; c < 4; ++c) {
      const float m_ = redm[tid][c]; const int i_ = redi[tid][c];
      if (m_ < bm || (m_ == bm && i_ < bi)) { bm = m_; bi = i_; }
    }
    idxs[tid] = bi;
    tot += bm;
  }
#pragma unroll
  for (int m = 1; m < 64; m <<= 1) tot += __shfl_xor(tot, m, 64);
  if (lane == 0) wpart[wid] = tot;
  __syncthreads();
  if (tid == 0) {
    double s = 0.0;
    for (int i = 0; i < 8; ++i) s += (double)wpart[i];
    atomicAdd(&lsum[blockIdx.x & 63], s);
  }

  for (int g = tid; g < FBM * (DIM / 4); g += FNT) {
    const int row = g >> 7;
    const int d4 = (g & 127) * 4;
    const int idx = idxs[row];
    *(float4*)&outq[(size_t)(row0 + row) * DIM + d4] =
        *(const float4*)&CB[(size_t)idx * DIM + d4];
  }
}

__global__ void vq_norms_kernel(const float* __restrict__ cb,
                                float* __restrict__ norms) {
  const int gw = (int)((blockIdx.x * blockDim.x + threadIdx.x) >> 6);
  const int l = threadIdx.x & 63;
  const float4 a = *(const float4*)&cb[(size_t)gw * DIM + l * 8];
  const float4 b = *(const float4*)&cb[(size_t)gw * DIM + l * 8 + 4];
  float s = a.x * a.x + a.y * a.y + a.z * a.z + a.w * a.w +
            b.x * b.x + b.y * b.y + b.z * b.z + b.w * b.w;
#pragma unroll
  for (int m = 1; m < 64; m <<= 1) s += __shfl_xor(s, m, 64);
  if (l == 0) norms[gw] = s;
}

__global__ void vq_finalize_kernel(const double* __restrict__ lsum,
                                   float* __restrict__ out) {
  double t = 0.0;
  for (int i = 0; i < 64; ++i) t += lsum[i];
  out[0] = (float)(1.25 * t / (double)((size_t)LAT_ROWS * DIM));
}

extern "C" void kernel_launch(void* const* d_in, const int* in_sizes, int n_in,
                              void* d_out, int out_size, void* d_ws, size_t ws_size,
                              hipStream_t stream) {
  const float* X = (const float*)d_in[0];     // [32768, 512] f32
  const float* CB = (const float*)d_in[1];    // [1024, 512] f32
  float* out = (float*)d_out;                 // quantized [16777216] + loss [1]
  double* lsum = (double*)((char*)d_ws + WS_LSUM);   // 64 doubles
  float* norms = (float*)((char*)d_ws + WS_NORM);    // 1024 f32

  hipMemsetAsync(d_ws, 0, 512, stream);
  if (ws_size >= WS_NEEDED) {
    u16* CBbf = (u16*)((char*)d_ws + WS_CBBF);
    u16* Xbf = (u16*)((char*)d_ws + WS_XBF);
    vq_prep<<<4352, NTP, 0, stream>>>(X, CB, Xbf, CBbf, norms, lsum);
    vq_main7<<<LAT_ROWS / BM, NTM, 0, stream>>>(Xbf, CBbf, CB, norms, out, lsum);
  } else {
    vq_norms_kernel<<<KCODES / 4, 256, 0, stream>>>(CB, norms);
    vq_main_fb<<<LAT_ROWS / FBM, FNT, 0, stream>>>(X, CB, norms, out, lsum);
  }
  vq_finalize_kernel<<<1, 1, 0, stream>>>(lsum, out + (size_t)LAT_ROWS * DIM);
}

// Round 7
// 84.601 us; speedup vs baseline: 1.3758x; 1.3758x over previous
//
#include <hip/hip_runtime.h>
#include <cfloat>

#define LAT_ROWS 32768
#define DIM 512
#define KCODES 1024

// ---- round-5 geometry: 2 blocks/CU ----
constexpr int BM = 64;             // latent rows per block
constexpr int BN = 256;            // codes per code-tile
constexpr int BK = 64;             // d-chunk
constexpr int NT = 512;            // 8 waves: 4 code-groups x 2 row-groups
constexpr int NCT = KCODES / BN;   // 4
constexpr int NDK = DIM / BK;      // 8
constexpr int TT = NCT * NDK;      // 32
constexpr int CUNITS = BN * BK / 8;   // 2048 16B-units per CB tile

// workspace layout (bytes)
constexpr size_t WS_LSUM = 0;                      // 64 doubles
constexpr size_t WS_NORM = 512;                    // 1024 f32
constexpr size_t WS_CBBF = 4608;                   // 1 MB bf16 (swizzled tiles)
constexpr size_t WS_XBF  = 1053696;                // 32 MB bf16 (fragment-linear)
constexpr size_t WS_NEEDED = WS_XBF + (size_t)LAT_ROWS * DIM * 2;  // 34,608,128

typedef short bf16x8 __attribute__((ext_vector_type(8)));
typedef float f32x4 __attribute__((ext_vector_type(4)));
typedef unsigned short u16;
typedef u16 u16x8 __attribute__((ext_vector_type(8)));

__device__ __forceinline__ u16 f2bf(float f) {  // round-to-nearest-even
  unsigned u = __float_as_uint(f);
  u += 0x7FFF + ((u >> 16) & 1);
  return (u16)(u >> 16);
}

#define GLOAD_LDS(g, l)                                     \
  __builtin_amdgcn_global_load_lds(                         \
      (const __attribute__((address_space(1))) void*)(g),   \
      (__attribute__((address_space(3))) void*)(l), 16, 0, 0)

// ------------- prep: X->bf16 fragment-linear + sum(x^2); CB->bf16 tiles; norms -------------
// Xbf unit index: ((((b*8+dk)*2+wn)*2+nf)*2+ks)*64 + lane   (lane = l4*16+l15)
// content: rows r = b*64+wn*32+nf*16+l15, dims d0 = dk*64+ks*32+l4*8 (8 bf16)
__global__ void __launch_bounds__(NT)
vq_prep(const float* __restrict__ X, const float* __restrict__ CB,
        u16* __restrict__ Xbf, u16* __restrict__ CBbf,
        float* __restrict__ norms, double* __restrict__ lsum) {
  __shared__ float sp[8];
  const int bb = blockIdx.x;
  const int tid = threadIdx.x;
  if (bb < 4096) {  // ---- X convert
    const int id = bb * NT + tid;          // 0 .. 2^21-1
    const int l15 = id & 15;
    const int l4 = (id >> 4) & 3;
    const int ks = (id >> 6) & 1;
    const int nf = (id >> 7) & 1;
    const int wn = (id >> 8) & 1;
    const int dk = (id >> 9) & 7;
    const int b = id >> 12;
    const int r = b * 64 + wn * 32 + nf * 16 + l15;
    const int d0 = dk * 64 + ks * 32 + l4 * 8;
    const float* src = X + (size_t)r * DIM + d0;
    const float4 a = *(const float4*)src;
    const float4 c = *(const float4*)(src + 4);
    float s = a.x * a.x + a.y * a.y + a.z * a.z + a.w * a.w +
              c.x * c.x + c.y * c.y + c.z * c.z + c.w * c.w;
    u16x8 v;
    v[0] = f2bf(a.x); v[1] = f2bf(a.y); v[2] = f2bf(a.z); v[3] = f2bf(a.w);
    v[4] = f2bf(c.x); v[5] = f2bf(c.y); v[6] = f2bf(c.z); v[7] = f2bf(c.w);
    *(u16x8*)(Xbf + (size_t)id * 8) = v;
#pragma unroll
    for (int m = 1; m < 64; m <<= 1) s += __shfl_xor(s, m, 64);
    const int lane = tid & 63, w = tid >> 6;
    if (lane == 0) sp[w] = s;
    __syncthreads();
    if (tid == 0) {
      double t = 0.0;
      for (int i = 0; i < 8; ++i) t += (double)sp[i];
      atomicAdd(&lsum[bb & 63], t);
    }
  } else if (bb < 4224) {  // ---- CB convert: swizzled tile unit (ct,dk)
    const int id = (bb - 4096) * NT + tid;  // 0 .. 65535
    const int ct = id >> 14;
    const int rem = id & 16383;
    const int dk = rem >> 11;
    const int u = rem & 2047;
    const int r = u >> 3, qp = u & 7, q = qp ^ (r & 7);
    const float* src = CB + ((size_t)ct * BN + r) * DIM + dk * BK + q * 8;
    const float4 a = *(const float4*)src;
    const float4 c = *(const float4*)(src + 4);
    u16x8 v;
    v[0] = f2bf(a.x); v[1] = f2bf(a.y); v[2] = f2bf(a.z); v[3] = f2bf(a.w);
    v[4] = f2bf(c.x); v[5] = f2bf(c.y); v[6] = f2bf(c.z); v[7] = f2bf(c.w);
    *(u16x8*)(CBbf + (size_t)id * 8) = v;
  } else {  // ---- norms (f32 exact): one wave per code
    const int gw = (bb - 4224) * 8 + (tid >> 6);
    const int l = tid & 63;
    const float4 a = *(const float4*)&CB[(size_t)gw * DIM + l * 8];
    const float4 b = *(const float4*)&CB[(size_t)gw * DIM + l * 8 + 4];
    float s = a.x * a.x + a.y * a.y + a.z * a.z + a.w * a.w +
              b.x * b.x + b.y * b.y + b.z * b.z + b.w * b.w;
#pragma unroll
    for (int m = 1; m < 64; m <<= 1) s += __shfl_xor(s, m, 64);
    if (l == 0) norms[gw] = s;
  }
}

// ------- main: round-5 tile + reg-dbuf X prefetch + counted-vmcnt barrier + XCD swizzle -------
__global__ void __launch_bounds__(NT, 4)
vq_main8(const u16* __restrict__ Xbf, const u16* __restrict__ CBbf,
         const float* __restrict__ CB, const float* __restrict__ norms,
         float* __restrict__ outq, double* __restrict__ lsum) {
  __shared__ u16 Cs[2][CUNITS * 8];   // 32 KB x2
  __shared__ float snorm[KCODES];     // 4 KB
  __shared__ float redm[BM][4];
  __shared__ int redi[BM][4];
  __shared__ int idxs[BM];
  __shared__ float wpart[8];

  const int tid = threadIdx.x;
  const int lane = tid & 63;
  const int l15 = lane & 15;
  const int l4 = lane >> 4;
  const int wid = tid >> 6;
  const int wm = wid & 3;        // code group (64 codes)
  const int wn = wid >> 2;       // row group (32 rows)

  // XCD-aware bijective swizzle (grid = 512, 512 % 8 == 0)
  const int bid = blockIdx.x;
  const int b = (bid & 7) * ((int)gridDim.x >> 3) + (bid >> 3);
  const int row0 = b * BM;

  for (int i = tid; i < KCODES; i += NT) snorm[i] = norms[i];

  // per-wave X fragment base (fragment-linear; one coalesced 16B/lane load per frag)
  const u16* xw = Xbf + ((size_t)b * 4096 + wn * 256 + lane) * 8;

  auto stage = [&](int bf, int t) {   // 4 gload_lds per thread (CB tile only)
    const int ct = t >> 3, dk = t & 7;
    const u16* cp = CBbf + (size_t)(ct * NDK + dk) * CUNITS * 8;
#pragma unroll
    for (int k = 0; k < 4; ++k) {
      const int u = tid + k * NT;
      GLOAD_LDS(cp + (size_t)u * 8, &Cs[bf][u * 8]);
    }
  };

  f32x4 acc[4][2];                 // [mf codes][nf rows]
  float rmin[2]; int ridx[2];
#pragma unroll
  for (int i = 0; i < 2; ++i) { rmin[i] = FLT_MAX; ridx[i] = 0; }

  bf16x8 bfrA[2][2], bfrB[2][2];   // [ks][nf] register double-buffer for X frags

  // prologue: stage tile 0, preload X frags for t=0, full drain once
  stage(0, 0);
#pragma unroll
  for (int ks = 0; ks < 2; ++ks)
#pragma unroll
    for (int nf = 0; nf < 2; ++nf)
      bfrA[ks][nf] = *(const bf16x8*)(xw + (size_t)(nf * 128 + ks * 64) * 8);
  __syncthreads();

  // One iteration. BCUR holds this tile's X frags; BNXT gets t+1's.
  // vmcnt order per wave: stage(t+1) = 4 oldest, BNXT loads = 4 newest.
  // vmcnt(4) at the barrier completes exactly the stage; X prefetch spans it.
#define VQ_PHASE(T, BCUR, BNXT)                                               \
  {                                                                           \
    const int t_ = (T);                                                       \
    const int dk_ = t_ & 7;                                                   \
    const int cur_ = t_ & 1;                                                  \
    const bool pre_ = (t_ + 1 < TT);                                          \
    if (pre_) {                                                               \
      stage(cur_ ^ 1, t_ + 1);                                                \
      const u16* xq = xw + (size_t)(((t_ + 1) & 7) * 512) * 8;                \
      _Pragma("unroll") for (int ks = 0; ks < 2; ++ks)                        \
      _Pragma("unroll") for (int nf = 0; nf < 2; ++nf)                        \
        BNXT[ks][nf] = *(const bf16x8*)(xq + (size_t)(nf * 128 + ks * 64) * 8); \
    }                                                                         \
    if (dk_ == 0) {                                                           \
      const f32x4 z_ = {0.f, 0.f, 0.f, 0.f};                                  \
      _Pragma("unroll") for (int mf = 0; mf < 4; ++mf)                        \
      _Pragma("unroll") for (int nf = 0; nf < 2; ++nf) acc[mf][nf] = z_;      \
    }                                                                         \
    _Pragma("unroll") for (int ks = 0; ks < 2; ++ks) {                        \
      bf16x8 af_[4];                                                          \
      _Pragma("unroll") for (int mf = 0; mf < 4; ++mf) {                      \
        const int r_ = wm * 64 + mf * 16 + l15;                               \
        const int ph_ = (ks * 4 + l4) ^ (r_ & 7);                             \
        af_[mf] = *(const bf16x8*)&Cs[cur_][(r_ * 8 + ph_) * 8];              \
      }                                                                       \
      __builtin_amdgcn_s_setprio(1);                                          \
      _Pragma("unroll") for (int mf = 0; mf < 4; ++mf)                        \
      _Pragma("unroll") for (int nf = 0; nf < 2; ++nf)                        \
        acc[mf][nf] = __builtin_amdgcn_mfma_f32_16x16x32_bf16(                \
            af_[mf], BCUR[ks][nf], acc[mf][nf], 0, 0, 0);                     \
      __builtin_amdgcn_s_setprio(0);                                          \
    }                                                                         \
    if (dk_ == NDK - 1) {                                                     \
      const int ct_ = t_ >> 3;                                                \
      _Pragma("unroll") for (int mf = 0; mf < 4; ++mf) {                      \
        _Pragma("unroll") for (int r = 0; r < 4; ++r) {                       \
          const int code_ = ct_ * BN + wm * 64 + mf * 16 + l4 * 4 + r;        \
          const float cn_ = snorm[code_];                                     \
          _Pragma("unroll") for (int nf = 0; nf < 2; ++nf) {                  \
            const float s_ = fmaf(-2.f, acc[mf][nf][r], cn_);                 \
            if (s_ < rmin[nf]) { rmin[nf] = s_; ridx[nf] = code_; }           \
          }                                                                   \
        }                                                                     \
      }                                                                       \
    }                                                                         \
    if (pre_) asm volatile("s_waitcnt vmcnt(4)" ::: "memory");                \
    else      asm volatile("s_waitcnt vmcnt(0)" ::: "memory");                \
    __builtin_amdgcn_s_barrier();                                             \
  }

  for (int tt = 0; tt < TT; tt += 2) {
    VQ_PHASE(tt, bfrA, bfrB);
    VQ_PHASE(tt + 1, bfrB, bfrA);
  }
#undef VQ_PHASE

  // cross-lane argmin (lanes l15, +16, +32, +48 share a row; tie -> lowest idx)
#pragma unroll
  for (int m = 16; m <= 32; m <<= 1) {
#pragma unroll
    for (int nf = 0; nf < 2; ++nf) {
      const float om = __shfl_xor(rmin[nf], m, 64);
      const int oi = __shfl_xor(ridx[nf], m, 64);
      if (om < rmin[nf] || (om == rmin[nf] && oi < ridx[nf])) {
        rmin[nf] = om; ridx[nf] = oi;
      }
    }
  }
  if (l4 == 0) {
#pragma unroll
    for (int nf = 0; nf < 2; ++nf) {
      const int row = wn * 32 + nf * 16 + l15;
      redm[row][wm] = rmin[nf];
      redi[row][wm] = ridx[nf];
    }
  }
  __syncthreads();

  float tot = 0.f;
  if (tid < BM) {   // cross-wave reduce (4 code-group waves per row)
    float bm = redm[tid][0]; int bi = redi[tid][0];
#pragma unroll
    for (int c = 1; c < 4; ++c) {
      const float m_ = redm[tid][c]; const int i_ = redi[tid][c];
      if (m_ < bm || (m_ == bm && i_ < bi)) { bm = m_; bi = i_; }
    }
    idxs[tid] = bi;
    tot = bm;       // min(||c||^2 - 2 x.c); sum(x^2) added by prep pass
  }
#pragma unroll
  for (int m = 1; m < 64; m <<= 1) tot += __shfl_xor(tot, m, 64);
  if (lane == 0) wpart[wid] = tot;
  __syncthreads();
  if (tid == 0) {
    double s = 0.0;
    for (int i = 0; i < 8; ++i) s += (double)wpart[i];
    atomicAdd(&lsum[blockIdx.x & 63], s);
  }

  // gather + write quantized (exact f32 codebook rows, CB is L2-hot)
  for (int g = tid; g < BM * (DIM / 4); g += NT) {
    const int row = g >> 7;
    const int d4 = (g & 127) * 4;
    const int idx = idxs[row];
    *(float4*)&outq[(size_t)(row0 + row) * DIM + d4] =
        *(const float4*)&CB[(size_t)idx * DIM + d4];
  }
}

// ------------- fallback (round-2 path, small workspace; own constants) -------------
constexpr int FBM = 128, FBN = 256, FBK = 64, FNT = 512, FNDK = 8, FTT = 32;

__global__ void __launch_bounds__(FNT, 2)
vq_main_fb(const float* __restrict__ X, const float* __restrict__ CB,
           const float* __restrict__ norms, float* __restrict__ outq,
           double* __restrict__ lsum) {
  __shared__ u16 Xs[2][FBM * FBK];
  __shared__ u16 Cs[2][FBN * FBK];
  __shared__ float snorm[KCODES];
  __shared__ float redm[FBM][4];
  __shared__ int redi[FBM][4];
  __shared__ int idxs[FBM];
  __shared__ float wpart[8];

  const int tid = threadIdx.x;
  const int lane = tid & 63;
  const int l15 = lane & 15;
  const int l4 = lane >> 4;
  const int wid = tid >> 6;
  const int wm = wid & 3;
  const int wn = wid >> 2;
  const int row0 = blockIdx.x * FBM;

  for (int i = tid; i < KCODES; i += FNT) snorm[i] = norms[i];

  int xlds[2]; const float* xbase[2];
#pragma unroll
  for (int k = 0; k < 2; ++k) {
    const int u = tid + k * FNT;
    const int r = u >> 3, q = u & 7, ph = q ^ (r & 7);
    xlds[k] = r * FBK + ph * 8;
    xbase[k] = X + (size_t)(row0 + r) * DIM + q * 8;
  }
  int clds[4]; const float* cbase[4];
#pragma unroll
  for (int k = 0; k < 4; ++k) {
    const int u = tid + k * FNT;
    const int r = u >> 3, q = u & 7, ph = q ^ (r & 7);
    clds[k] = r * FBK + ph * 8;
    cbase[k] = CB + (size_t)r * DIM + q * 8;
  }

  f32x4 acc[4][4];
  float rmin[4]; int ridx[4];
#pragma unroll
  for (int i = 0; i < 4; ++i) { rmin[i] = FLT_MAX; ridx[i] = 0; }
  float sq = 0.f;

  float4 lx[2][2], lc[4][2];
  auto load_tile = [&](int tn) {
    const int ct = tn >> 3, dk = tn & 7;
    const int xo = dk * FBK;
    const size_t co = (size_t)ct * FBN * DIM + dk * FBK;
#pragma unroll
    for (int k = 0; k < 2; ++k) {
      lx[k][0] = *(const float4*)(xbase[k] + xo);
      lx[k][1] = *(const float4*)(xbase[k] + xo + 4);
    }
#pragma unroll
    for (int k = 0; k < 4; ++k) {
      lc[k][0] = *(const float4*)(cbase[k] + co);
      lc[k][1] = *(const float4*)(cbase[k] + co + 4);
    }
  };
  auto write_tile = [&](int bb, bool acc_sq) {
#pragma unroll
    for (int k = 0; k < 2; ++k) {
      u16x8 v;
      const float* f = (const float*)&lx[k][0];
#pragma unroll
      for (int j = 0; j < 8; ++j) {
        const float x = f[j];
        if (acc_sq) sq = fmaf(x, x, sq);
        v[j] = f2bf(x);
      }
      *(u16x8*)&Xs[bb][xlds[k]] = v;
    }
#pragma unroll
    for (int k = 0; k < 4; ++k) {
      u16x8 v;
      const float* f = (const float*)&lc[k][0];
#pragma unroll
      for (int j = 0; j < 8; ++j) v[j] = f2bf(f[j]);
      *(u16x8*)&Cs[bb][clds[k]] = v;
    }
  };

  load_tile(0);
  write_tile(0, true);
  __syncthreads();

  int cur = 0;
  for (int t = 0; t < FTT; ++t) {
    const int dk = t & 7;
    const bool pre = (t + 1 < FTT);
    if (pre) load_tile(t + 1);
    if (dk == 0) {
      const f32x4 z = {0.f, 0.f, 0.f, 0.f};
#pragma unroll
      for (int mf = 0; mf < 4; ++mf)
#pragma unroll
        for (int nf = 0; nf < 4; ++nf) acc[mf][nf] = z;
    }
    const u16* xb = Xs[cur];
    const u16* cb = Cs[cur];
#pragma unroll
    for (int ks = 0; ks < 2; ++ks) {
      bf16x8 af[4], bfr[4];
#pragma unroll
      for (int mf = 0; mf < 4; ++mf) {
        const int r = wm * 64 + mf * 16 + l15;
        const int ph = (ks * 4 + l4) ^ (r & 7);
        af[mf] = *(const bf16x8*)&cb[r * FBK + ph * 8];
      }
#pragma unroll
      for (int nf = 0; nf < 4; ++nf) {
        const int r = wn * 64 + nf * 16 + l15;
        const int ph = (ks * 4 + l4) ^ (r & 7);
        bfr[nf] = *(const bf16x8*)&xb[r * FBK + ph * 8];
      }
#pragma unroll
      for (int mf = 0; mf < 4; ++mf)
#pragma unroll
        for (int nf = 0; nf < 4; ++nf)
          acc[mf][nf] = __builtin_amdgcn_mfma_f32_16x16x32_bf16(
              af[mf], bfr[nf], acc[mf][nf], 0, 0, 0);
    }
    if (dk == FNDK - 1) {
      const int ct = t >> 3;
#pragma unroll
      for (int mf = 0; mf < 4; ++mf) {
#pragma unroll
        for (int r = 0; r < 4; ++r) {
          const int code = ct * FBN + wm * 64 + mf * 16 + l4 * 4 + r;
          const float cn = snorm[code];
#pragma unroll
          for (int nf = 0; nf < 4; ++nf) {
            const float s = fmaf(-2.f, acc[mf][nf][r], cn);
            if (s < rmin[nf]) { rmin[nf] = s; ridx[nf] = code; }
          }
        }
      }
    }
    if (pre) write_tile(cur ^ 1, (t + 1) < FNDK);
    __syncthreads();
    cur ^= 1;
  }

#pragma unroll
  for (int m = 16; m <= 32; m <<= 1) {
#pragma unroll
    for (int nf = 0; nf < 4; ++nf) {
      const float om = __shfl_xor(rmin[nf], m, 64);
      const int oi = __shfl_xor(ridx[nf], m, 64);
      if (om < rmin[nf] || (om == rmin[nf] && oi < ridx[nf])) {
        rmin[nf] = om; ridx[nf] = oi;
      }
    }
  }
  if (l4 == 0) {
#pragma unroll
    for (int nf = 0; nf < 4; ++nf) {
      const int row = wn * 64 + nf * 16 + l15;
      redm[row][wm] = rmin[nf];
      redi[row][wm] = ridx[nf];
    }
  }
  __syncthreads();

  float tot = sq;
  if (tid < FBM) {
    float bm = redm[tid][0]; int bi = redi[tid][0];
#pragma unroll
    for (int c = 1; c < 4; ++c) {
      const float m_ = redm[tid][c]; const int i_ = redi[tid][c];
      if (m_ < bm || (m_ == bm && i_ < bi)) { bm = m_; bi = i_; }
    }
    idxs[tid] = bi;
    tot += bm;
  }
#pragma unroll
  for (int m = 1; m < 64; m <<= 1) tot += __shfl_xor(tot, m, 64);
  if (lane == 0) wpart[wid] = tot;
  __syncthreads();
  if (tid == 0) {
    double s = 0.0;
    for (int i = 0; i < 8; ++i) s += (double)wpart[i];
    atomicAdd(&lsum[blockIdx.x & 63], s);
  }

  for (int g = tid; g < FBM * (DIM / 4); g += FNT) {
    const int row = g >> 7;
    const int d4 = (g & 127) * 4;
    const int idx = idxs[row];
    *(float4*)&outq[(size_t)(row0 + row) * DIM + d4] =
        *(const float4*)&CB[(size_t)idx * DIM + d4];
  }
}

__global__ void vq_norms_kernel(const float* __restrict__ cb,
                                float* __restrict__ norms) {
  const int gw = (int)((blockIdx.x * blockDim.x + threadIdx.x) >> 6);
  const int l = threadIdx.x & 63;
  const float4 a = *(const float4*)&cb[(size_t)gw * DIM + l * 8];
  const float4 b = *(const float4*)&cb[(size_t)gw * DIM + l * 8 + 4];
  float s = a.x * a.x + a.y * a.y + a.z * a.z + a.w * a.w +
            b.x * b.x + b.y * b.y + b.z * b.z + b.w * b.w;
#pragma unroll
  for (int m = 1; m < 64; m <<= 1) s += __shfl_xor(s, m, 64);
  if (l == 0) norms[gw] = s;
}

__global__ void vq_finalize_kernel(const double* __restrict__ lsum,
                                   float* __restrict__ out) {
  double t = 0.0;
  for (int i = 0; i < 64; ++i) t += lsum[i];
  out[0] = (float)(1.25 * t / (double)((size_t)LAT_ROWS * DIM));
}

extern "C" void kernel_launch(void* const* d_in, const int* in_sizes, int n_in,
                              void* d_out, int out_size, void* d_ws, size_t ws_size,
                              hipStream_t stream) {
  const float* X = (const float*)d_in[0];     // [32768, 512] f32
  const float* CB = (const float*)d_in[1];    // [1024, 512] f32
  float* out = (float*)d_out;                 // quantized [16777216] + loss [1]
  double* lsum = (double*)((char*)d_ws + WS_LSUM);   // 64 doubles
  float* norms = (float*)((char*)d_ws + WS_NORM);    // 1024 f32

  hipMemsetAsync(d_ws, 0, 512, stream);
  if (ws_size >= WS_NEEDED) {
    u16* CBbf = (u16*)((char*)d_ws + WS_CBBF);
    u16* Xbf = (u16*)((char*)d_ws + WS_XBF);
    vq_prep<<<4352, NT, 0, stream>>>(X, CB, Xbf, CBbf, norms, lsum);
    vq_main8<<<LAT_ROWS / BM, NT, 0, stream>>>(Xbf, CBbf, CB, norms, out, lsum);
  } else {
    vq_norms_kernel<<<KCODES / 4, 256, 0, stream>>>(CB, norms);
    vq_main_fb<<<LAT_ROWS / FBM, FNT, 0, stream>>>(X, CB, norms, out, lsum);
  }
  vq_finalize_kernel<<<1, 1, 0, stream>>>(lsum, out + (size_t)LAT_ROWS * DIM);
}

// Round 8
// 69.014 us; speedup vs baseline: 1.6865x; 1.2259x over previous
//
#include <hip/hip_runtime.h>
#include <cfloat>

#define LAT_ROWS 32768
#define DIM 512
#define KCODES 1024

// ---- geometry (round-5 winner): 2 blocks/CU ----
constexpr int BM = 64;             // latent rows per block
constexpr int BN = 256;            // codes per code-tile
constexpr int BK = 64;             // d-chunk
constexpr int NT = 512;            // 8 waves: 4 code-groups x 2 row-groups
constexpr int NCT = KCODES / BN;   // 4
constexpr int NDK = DIM / BK;      // 8
constexpr int TT = NCT * NDK;      // 32
constexpr int CUNITS = BN * BK / 8;   // 2048 8B-units per fp8 CB tile (16 KB)

// workspace layout (bytes)
constexpr size_t WS_LSUM = 0;                      // 64 doubles
constexpr size_t WS_NORM = 512;                    // 1024 f32
constexpr size_t WS_CBF8 = 4608;                   // 512 KB fp8 (swizzled tiles)
constexpr size_t WS_XF8  = 4608 + 524288;          // 16 MB fp8 (fragment-linear)
constexpr size_t WS_NEEDED = WS_XF8 + (size_t)LAT_ROWS * DIM;  // ~17.3 MB

typedef float f32x4 __attribute__((ext_vector_type(4)));
typedef short bf16x8 __attribute__((ext_vector_type(8)));
typedef unsigned short u16;
typedef u16 u16x8 __attribute__((ext_vector_type(8)));

__device__ __forceinline__ u16 f2bf(float f) {  // round-to-nearest-even (fallback path)
  unsigned u = __float_as_uint(f);
  u += 0x7FFF + ((u >> 16) & 1);
  return (u16)(u >> 16);
}

// pack 8 f32 -> 8 fp8 e4m3 (RNE via v_cvt_pk_fp8_f32)
__device__ __forceinline__ int2 pk8_fp8(const float4 a, const float4 c) {
  int lo = __builtin_amdgcn_cvt_pk_fp8_f32(a.x, a.y, 0, false);
  lo = __builtin_amdgcn_cvt_pk_fp8_f32(a.z, a.w, lo, true);
  int hi = __builtin_amdgcn_cvt_pk_fp8_f32(c.x, c.y, 0, false);
  hi = __builtin_amdgcn_cvt_pk_fp8_f32(c.z, c.w, hi, true);
  int2 v; v.x = lo; v.y = hi;
  return v;
}

#define GLOAD_LDS(g, l)                                     \
  __builtin_amdgcn_global_load_lds(                         \
      (const __attribute__((address_space(1))) void*)(g),   \
      (__attribute__((address_space(3))) void*)(l), 16, 0, 0)

// ------------- prep: X->fp8 fragment-linear + sum(x^2); CB->fp8 tiles; norms -------------
// Xf8 unit (8B): idx = b*4096 + dk*512 + wn*256 + nf*128 + ks*64 + lane
// content: row r = b*64+wn*32+nf*16+(lane&15), dims d0 = dk*64+ks*32+(lane>>4)*8
__global__ void __launch_bounds__(NT)
vq_prep(const float* __restrict__ X, const float* __restrict__ CB,
        long* __restrict__ Xf8, long* __restrict__ CBf8,
        float* __restrict__ norms, double* __restrict__ lsum) {
  __shared__ float sp[8];
  const int bb = blockIdx.x;
  const int tid = threadIdx.x;
  if (bb < 4096) {  // ---- X convert
    const int id = bb * NT + tid;          // 0 .. 2^21-1
    const int l15 = id & 15;
    const int l4 = (id >> 4) & 3;
    const int ks = (id >> 6) & 1;
    const int nf = (id >> 7) & 1;
    const int wn = (id >> 8) & 1;
    const int dk = (id >> 9) & 7;
    const int b = id >> 12;
    const int r = b * 64 + wn * 32 + nf * 16 + l15;
    const int d0 = dk * 64 + ks * 32 + l4 * 8;
    const float* src = X + (size_t)r * DIM + d0;
    const float4 a = *(const float4*)src;
    const float4 c = *(const float4*)(src + 4);
    float s = a.x * a.x + a.y * a.y + a.z * a.z + a.w * a.w +
              c.x * c.x + c.y * c.y + c.z * c.z + c.w * c.w;
    *(int2*)(Xf8 + id) = pk8_fp8(a, c);
#pragma unroll
    for (int m = 1; m < 64; m <<= 1) s += __shfl_xor(s, m, 64);
    const int lane = tid & 63, w = tid >> 6;
    if (lane == 0) sp[w] = s;
    __syncthreads();
    if (tid == 0) {
      double t = 0.0;
      for (int i = 0; i < 8; ++i) t += (double)sp[i];
      atomicAdd(&lsum[bb & 63], t);
    }
  } else if (bb < 4224) {  // ---- CB convert: swizzled tile unit (ct,dk)
    const int id = (bb - 4096) * NT + tid;  // 0 .. 65535
    const int ct = id >> 14;
    const int dk = (id >> 11) & 7;
    const int u = id & 2047;
    const int r = u >> 3, qp = u & 7, q = qp ^ (r & 7);
    const float* src = CB + ((size_t)ct * BN + r) * DIM + dk * BK + q * 8;
    const float4 a = *(const float4*)src;
    const float4 c = *(const float4*)(src + 4);
    *(int2*)(CBf8 + id) = pk8_fp8(a, c);
  } else {  // ---- norms (f32 exact): one wave per code
    const int gw = (bb - 4224) * 8 + (tid >> 6);
    const int l = tid & 63;
    const float4 a = *(const float4*)&CB[(size_t)gw * DIM + l * 8];
    const float4 b = *(const float4*)&CB[(size_t)gw * DIM + l * 8 + 4];
    float s = a.x * a.x + a.y * a.y + a.z * a.z + a.w * a.w +
              b.x * b.x + b.y * b.y + b.z * b.z + b.w * b.w;
#pragma unroll
    for (int m = 1; m < 64; m <<= 1) s += __shfl_xor(s, m, 64);
    if (l == 0) norms[gw] = s;
  }
}

// ------- main: fp8 MFMA, CB dbuf in LDS via gload_lds, X frags direct from global -------
__global__ void __launch_bounds__(NT, 4)
vq_main9(const long* __restrict__ Xf8, const long* __restrict__ CBf8,
         const float* __restrict__ CB, const float* __restrict__ norms,
         float* __restrict__ outq, double* __restrict__ lsum) {
  __shared__ long Cs[2][CUNITS];      // 16 KB x2
  __shared__ float snorm[KCODES];     // 4 KB
  __shared__ float redm[BM][4];
  __shared__ int redi[BM][4];
  __shared__ int idxs[BM];
  __shared__ float wpart[8];

  const int tid = threadIdx.x;
  const int lane = tid & 63;
  const int l15 = lane & 15;
  const int l4 = lane >> 4;
  const int wid = tid >> 6;
  const int wm = wid & 3;        // code group (64 codes)
  const int wn = wid >> 2;       // row group (32 rows)
  const int b = blockIdx.x;
  const int row0 = b * BM;

  for (int i = tid; i < KCODES; i += NT) snorm[i] = norms[i];

  // per-wave X fragment base (fragment-linear; one coalesced 8B/lane load per frag)
  const long* xw = Xf8 + (size_t)b * 4096 + wn * 256 + lane;

  auto stage = [&](int bf, int t) {   // 2 gload_lds (16B) per thread -> 16 KB tile
    const int ct = t >> 3, dk = t & 7;
    const char* cp = (const char*)(CBf8 + (size_t)(ct * NDK + dk) * CUNITS);
    char* dst = (char*)&Cs[bf][0];
#pragma unroll
    for (int k = 0; k < 2; ++k) {
      const int o = (tid + k * NT) * 16;
      GLOAD_LDS(cp + o, dst + o);
    }
  };

  f32x4 acc[4][2];                 // [mf codes][nf rows]
  float rmin[2]; int ridx[2];
#pragma unroll
  for (int i = 0; i < 2; ++i) { rmin[i] = FLT_MAX; ridx[i] = 0; }

  stage(0, 0);
  __syncthreads();

  for (int t = 0; t < TT; ++t) {
    const int dk = t & 7;
    const int cur = t & 1;
    // X fragments first (older in vmcnt order than the stage prefetch)
    long bfr[2][2];   // [ks][nf]
    const long* xp = xw + dk * 512;
#pragma unroll
    for (int ks = 0; ks < 2; ++ks)
#pragma unroll
      for (int nf = 0; nf < 2; ++nf)
        bfr[ks][nf] = xp[nf * 128 + ks * 64];
    if (t + 1 < TT) stage(cur ^ 1, t + 1);   // prefetch stays in flight past bfr waits

    if (dk == 0) {
      const f32x4 z = {0.f, 0.f, 0.f, 0.f};
#pragma unroll
      for (int mf = 0; mf < 4; ++mf)
#pragma unroll
        for (int nf = 0; nf < 2; ++nf) acc[mf][nf] = z;
    }
#pragma unroll
    for (int ks = 0; ks < 2; ++ks) {
      long af[4];
#pragma unroll
      for (int mf = 0; mf < 4; ++mf) {
        const int r = wm * 64 + mf * 16 + l15;
        const int ph = (ks * 4 + l4) ^ (r & 7);
        af[mf] = Cs[cur][r * 8 + ph];
      }
      __builtin_amdgcn_s_setprio(1);
#pragma unroll
      for (int mf = 0; mf < 4; ++mf)
#pragma unroll
        for (int nf = 0; nf < 2; ++nf)
          acc[mf][nf] = __builtin_amdgcn_mfma_f32_16x16x32_fp8_fp8(
              af[mf], bfr[ks][nf], acc[mf][nf], 0, 0, 0);
      __builtin_amdgcn_s_setprio(0);
    }
    if (dk == NDK - 1) {  // fold finished code-tile into running argmin
      const int ct = t >> 3;
#pragma unroll
      for (int mf = 0; mf < 4; ++mf) {
#pragma unroll
        for (int r = 0; r < 4; ++r) {
          const int code = ct * BN + wm * 64 + mf * 16 + l4 * 4 + r;
          const float cn = snorm[code];
#pragma unroll
          for (int nf = 0; nf < 2; ++nf) {
            const float s = fmaf(-2.f, acc[mf][nf][r], cn);
            if (s < rmin[nf]) { rmin[nf] = s; ridx[nf] = code; }
          }
        }
      }
    }
    __syncthreads();   // buffer swap; co-resident block hides the drain
  }

  // cross-lane argmin (lanes l15, +16, +32, +48 share a row; tie -> lowest idx)
#pragma unroll
  for (int m = 16; m <= 32; m <<= 1) {
#pragma unroll
    for (int nf = 0; nf < 2; ++nf) {
      const float om = __shfl_xor(rmin[nf], m, 64);
      const int oi = __shfl_xor(ridx[nf], m, 64);
      if (om < rmin[nf] || (om == rmin[nf] && oi < ridx[nf])) {
        rmin[nf] = om; ridx[nf] = oi;
      }
    }
  }
  if (l4 == 0) {
#pragma unroll
    for (int nf = 0; nf < 2; ++nf) {
      const int row = wn * 32 + nf * 16 + l15;
      redm[row][wm] = rmin[nf];
      redi[row][wm] = ridx[nf];
    }
  }
  __syncthreads();

  float tot = 0.f;
  if (tid < BM) {   // cross-wave reduce (4 code-group waves per row)
    float bm = redm[tid][0]; int bi = redi[tid][0];
#pragma unroll
    for (int c = 1; c < 4; ++c) {
      const float m_ = redm[tid][c]; const int i_ = redi[tid][c];
      if (m_ < bm || (m_ == bm && i_ < bi)) { bm = m_; bi = i_; }
    }
    idxs[tid] = bi;
    tot = bm;       // min(||c||^2 - 2 x.c); sum(x^2) added by prep pass
  }
#pragma unroll
  for (int m = 1; m < 64; m <<= 1) tot += __shfl_xor(tot, m, 64);
  if (lane == 0) wpart[wid] = tot;
  __syncthreads();
  if (tid == 0) {
    double s = 0.0;
    for (int i = 0; i < 8; ++i) s += (double)wpart[i];
    atomicAdd(&lsum[blockIdx.x & 63], s);
  }

  // gather + write quantized (exact f32 codebook rows, CB is L2-hot)
  for (int g = tid; g < BM * (DIM / 4); g += NT) {
    const int row = g >> 7;
    const int d4 = (g & 127) * 4;
    const int idx = idxs[row];
    *(float4*)&outq[(size_t)(row0 + row) * DIM + d4] =
        *(const float4*)&CB[(size_t)idx * DIM + d4];
  }
}

// ------------- fallback (round-2 path, small workspace; own constants) -------------
constexpr int FBM = 128, FBN = 256, FBK = 64, FNT = 512, FNDK = 8, FTT = 32;

__global__ void __launch_bounds__(FNT, 2)
vq_main_fb(const float* __restrict__ X, const float* __restrict__ CB,
           const float* __restrict__ norms, float* __restrict__ outq,
           double* __restrict__ lsum) {
  __shared__ u16 Xs[2][FBM * FBK];
  __shared__ u16 Cs[2][FBN * FBK];
  __shared__ float snorm[KCODES];
  __shared__ float redm[FBM][4];
  __shared__ int redi[FBM][4];
  __shared__ int idxs[FBM];
  __shared__ float wpart[8];

  const int tid = threadIdx.x;
  const int lane = tid & 63;
  const int l15 = lane & 15;
  const int l4 = lane >> 4;
  const int wid = tid >> 6;
  const int wm = wid & 3;
  const int wn = wid >> 2;
  const int row0 = blockIdx.x * FBM;

  for (int i = tid; i < KCODES; i += FNT) snorm[i] = norms[i];

  int xlds[2]; const float* xbase[2];
#pragma unroll
  for (int k = 0; k < 2; ++k) {
    const int u = tid + k * FNT;
    const int r = u >> 3, q = u & 7, ph = q ^ (r & 7);
    xlds[k] = r * FBK + ph * 8;
    xbase[k] = X + (size_t)(row0 + r) * DIM + q * 8;
  }
  int clds[4]; const float* cbase[4];
#pragma unroll
  for (int k = 0; k < 4; ++k) {
    const int u = tid + k * FNT;
    const int r = u >> 3, q = u & 7, ph = q ^ (r & 7);
    clds[k] = r * FBK + ph * 8;
    cbase[k] = CB + (size_t)r * DIM + q * 8;
  }

  f32x4 acc[4][4];
  float rmin[4]; int ridx[4];
#pragma unroll
  for (int i = 0; i < 4; ++i) { rmin[i] = FLT_MAX; ridx[i] = 0; }
  float sq = 0.f;

  float4 lx[2][2], lc[4][2];
  auto load_tile = [&](int tn) {
    const int ct = tn >> 3, dk = tn & 7;
    const int xo = dk * FBK;
    const size_t co = (size_t)ct * FBN * DIM + dk * FBK;
#pragma unroll
    for (int k = 0; k < 2; ++k) {
      lx[k][0] = *(const float4*)(xbase[k] + xo);
      lx[k][1] = *(const float4*)(xbase[k] + xo + 4);
    }
#pragma unroll
    for (int k = 0; k < 4; ++k) {
      lc[k][0] = *(const float4*)(cbase[k] + co);
      lc[k][1] = *(const float4*)(cbase[k] + co + 4);
    }
  };
  auto write_tile = [&](int bb, bool acc_sq) {
#pragma unroll
    for (int k = 0; k < 2; ++k) {
      u16x8 v;
      const float* f = (const float*)&lx[k][0];
#pragma unroll
      for (int j = 0; j < 8; ++j) {
        const float x = f[j];
        if (acc_sq) sq = fmaf(x, x, sq);
        v[j] = f2bf(x);
      }
      *(u16x8*)&Xs[bb][xlds[k]] = v;
    }
#pragma unroll
    for (int k = 0; k < 4; ++k) {
      u16x8 v;
      const float* f = (const float*)&lc[k][0];
#pragma unroll
      for (int j = 0; j < 8; ++j) v[j] = f2bf(f[j]);
      *(u16x8*)&Cs[bb][clds[k]] = v;
    }
  };

  load_tile(0);
  write_tile(0, true);
  __syncthreads();

  int cur = 0;
  for (int t = 0; t < FTT; ++t) {
    const int dk = t & 7;
    const bool pre = (t + 1 < FTT);
    if (pre) load_tile(t + 1);
    if (dk == 0) {
      const f32x4 z = {0.f, 0.f, 0.f, 0.f};
#pragma unroll
      for (int mf = 0; mf < 4; ++mf)
#pragma unroll
        for (int nf = 0; nf < 4; ++nf) acc[mf][nf] = z;
    }
    const u16* xb = Xs[cur];
    const u16* cb = Cs[cur];
#pragma unroll
    for (int ks = 0; ks < 2; ++ks) {
      bf16x8 af[4], bfr[4];
#pragma unroll
      for (int mf = 0; mf < 4; ++mf) {
        const int r = wm * 64 + mf * 16 + l15;
        const int ph = (ks * 4 + l4) ^ (r & 7);
        af[mf] = *(const bf16x8*)&cb[r * FBK + ph * 8];
      }
#pragma unroll
      for (int nf = 0; nf < 4; ++nf) {
        const int r = wn * 64 + nf * 16 + l15;
        const int ph = (ks * 4 + l4) ^ (r & 7);
        bfr[nf] = *(const bf16x8*)&xb[r * FBK + ph * 8];
      }
#pragma unroll
      for (int mf = 0; mf < 4; ++mf)
#pragma unroll
        for (int nf = 0; nf < 4; ++nf)
          acc[mf][nf] = __builtin_amdgcn_mfma_f32_16x16x32_bf16(
              af[mf], bfr[nf], acc[mf][nf], 0, 0, 0);
    }
    if (dk == FNDK - 1) {
      const int ct = t >> 3;
#pragma unroll
      for (int mf = 0; mf < 4; ++mf) {
#pragma unroll
        for (int r = 0; r < 4; ++r) {
          const int code = ct * FBN + wm * 64 + mf * 16 + l4 * 4 + r;
          const float cn = snorm[code];
#pragma unroll
          for (int nf = 0; nf < 4; ++nf) {
            const float s = fmaf(-2.f, acc[mf][nf][r], cn);
            if (s < rmin[nf]) { rmin[nf] = s; ridx[nf] = code; }
          }
        }
      }
    }
    if (pre) write_tile(cur ^ 1, (t + 1) < FNDK);
    __syncthreads();
    cur ^= 1;
  }

#pragma unroll
  for (int m = 16; m <= 32; m <<= 1) {
#pragma unroll
    for (int nf = 0; nf < 4; ++nf) {
      const float om = __shfl_xor(rmin[nf], m, 64);
      const int oi = __shfl_xor(ridx[nf], m, 64);
      if (om < rmin[nf] || (om == rmin[nf] && oi < ridx[nf])) {
        rmin[nf] = om; ridx[nf] = oi;
      }
    }
  }
  if (l4 == 0) {
#pragma unroll
    for (int nf = 0; nf < 4; ++nf) {
      const int row = wn * 64 + nf * 16 + l15;
      redm[row][wm] = rmin[nf];
      redi[row][wm] = ridx[nf];
    }
  }
  __syncthreads();

  float tot = sq;
  if (tid < FBM) {
    float bm = redm[tid][0]; int bi = redi[tid][0];
#pragma unroll
    for (int c = 1; c < 4; ++c) {
      const float m_ = redm[tid][c]; const int i_ = redi[tid][c];
      if (m_ < bm || (m_ == bm && i_ < bi)) { bm = m_; bi = i_; }
    }
    idxs[tid] = bi;
    tot += bm;
  }
#pragma unroll
  for (int m = 1; m < 64; m <<= 1) tot += __shfl_xor(tot, m, 64);
  if (lane == 0) wpart[wid] = tot;
  __syncthreads();
  if (tid == 0) {
    double s = 0.0;
    for (int i = 0; i < 8; ++i) s += (double)wpart[i];
    atomicAdd(&lsum[blockIdx.x & 63], s);
  }

  for (int g = tid; g < FBM * (DIM / 4); g += FNT) {
    const int row = g >> 7;
    const int d4 = (g & 127) * 4;
    const int idx = idxs[row];
    *(float4*)&outq[(size_t)(row0 + row) * DIM + d4] =
        *(const float4*)&CB[(size_t)idx * DIM + d4];
  }
}

__global__ void vq_norms_kernel(const float* __restrict__ cb,
                                float* __restrict__ norms) {
  const int gw = (int)((blockIdx.x * blockDim.x + threadIdx.x) >> 6);
  const int l = threadIdx.x & 63;
  const float4 a = *(const float4*)&cb[(size_t)gw * DIM + l * 8];
  const float4 b = *(const float4*)&cb[(size_t)gw * DIM + l * 8 + 4];
  float s = a.x * a.x + a.y * a.y + a.z * a.z + a.w * a.w +
            b.x * b.x + b.y * b.y + b.z * b.z + b.w * b.w;
#pragma unroll
  for (int m = 1; m < 64; m <<= 1) s += __shfl_xor(s, m, 64);
  if (l == 0) norms[gw] = s;
}

__global__ void vq_finalize_kernel(const double* __restrict__ lsum,
                                   float* __restrict__ out) {
  double t = 0.0;
  for (int i = 0; i < 64; ++i) t += lsum[i];
  out[0] = (float)(1.25 * t / (double)((size_t)LAT_ROWS * DIM));
}

extern "C" void kernel_launch(void* const* d_in, const int* in_sizes, int n_in,
                              void* d_out, int out_size, void* d_ws, size_t ws_size,
                              hipStream_t stream) {
  const float* X = (const float*)d_in[0];     // [32768, 512] f32
  const float* CB = (const float*)d_in[1];    // [1024, 512] f32
  float* out = (float*)d_out;                 // quantized [16777216] + loss [1]
  double* lsum = (double*)((char*)d_ws + WS_LSUM);   // 64 doubles
  float* norms = (float*)((char*)d_ws + WS_NORM);    // 1024 f32

  hipMemsetAsync(d_ws, 0, 512, stream);
  if (ws_size >= WS_NEEDED) {
    long* CBf8 = (long*)((char*)d_ws + WS_CBF8);
    long* Xf8 = (long*)((char*)d_ws + WS_XF8);
    vq_prep<<<4352, NT, 0, stream>>>(X, CB, Xf8, CBf8, norms, lsum);
    vq_main9<<<LAT_ROWS / BM, NT, 0, stream>>>(Xf8, CBf8, CB, norms, out, lsum);
  } else {
    vq_norms_kernel<<<KCODES / 4, 256, 0, stream>>>(CB, norms);
    vq_main_fb<<<LAT_ROWS / FBM, FNT, 0, stream>>>(X, CB, norms, out, lsum);
  }
  vq_finalize_kernel<<<1, 1, 0, stream>>>(lsum, out + (size_t)LAT_ROWS * DIM);
}

// Round 9
// 65.152 us; speedup vs baseline: 1.7865x; 1.0593x over previous
//
#include <hip/hip_runtime.h>
#include <cfloat>

#define LAT_ROWS 32768
#define DIM 512
#define KCODES 1024

// ---- geometry: 2 blocks/CU, 2-dk merged phases ----
constexpr int BM = 64;             // latent rows per block
constexpr int BN = 256;            // codes per code-tile
constexpr int BK = 64;             // d-chunk
constexpr int NT = 512;            // 8 waves: 4 code-groups x 2 row-groups
constexpr int NCT = KCODES / BN;   // 4
constexpr int NDK = DIM / BK;      // 8
constexpr int NPH = 16;            // merged phases (2 dk each)
constexpr int CUNITS = BN * BK / 8;   // 2048 8B-units per fp8 CB tile (16 KB)

// workspace layout (bytes)
constexpr size_t WS_LSUM = 0;                      // 64 doubles
constexpr size_t WS_NORM = 512;                    // 1024 f32
constexpr size_t WS_CBF8 = 4608;                   // 512 KB fp8 (swizzled tiles)
constexpr size_t WS_XF8  = 4608 + 524288;          // 16 MB fp8 (fragment-linear)
constexpr size_t WS_NEEDED = WS_XF8 + (size_t)LAT_ROWS * DIM;  // ~17.3 MB

typedef float f32x4 __attribute__((ext_vector_type(4)));
typedef short bf16x8 __attribute__((ext_vector_type(8)));
typedef unsigned short u16;
typedef u16 u16x8 __attribute__((ext_vector_type(8)));

__device__ __forceinline__ u16 f2bf(float f) {  // RNE (fallback path)
  unsigned u = __float_as_uint(f);
  u += 0x7FFF + ((u >> 16) & 1);
  return (u16)(u >> 16);
}

// pack 8 f32 -> 8 fp8 e4m3 (RNE via v_cvt_pk_fp8_f32)
__device__ __forceinline__ int2 pk8_fp8(const float4 a, const float4 c) {
  int lo = __builtin_amdgcn_cvt_pk_fp8_f32(a.x, a.y, 0, false);
  lo = __builtin_amdgcn_cvt_pk_fp8_f32(a.z, a.w, lo, true);
  int hi = __builtin_amdgcn_cvt_pk_fp8_f32(c.x, c.y, 0, false);
  hi = __builtin_amdgcn_cvt_pk_fp8_f32(c.z, c.w, hi, true);
  int2 v; v.x = lo; v.y = hi;
  return v;
}

#define GLOAD_LDS(g, l)                                     \
  __builtin_amdgcn_global_load_lds(                         \
      (const __attribute__((address_space(1))) void*)(g),   \
      (__attribute__((address_space(3))) void*)(l), 16, 0, 0)

// ------------- prep -------------
// Xf8 unit (8B): idx = b*4096 + dk*512 + wn*256 + nf*128 + ks*64 + l4*16 + l15
// content: row r = b*64+wn*32+nf*16+l15, dims d0 = dk*64+ks*32+l4*8
// CBf8 tile (ct,dk): phys slot (r, qp) holds logical quad q = (qp + 8 - ((r>>1)&7)) & 7
__global__ void __launch_bounds__(NT)
vq_prep(const float* __restrict__ X, const float* __restrict__ CB,
        long* __restrict__ Xf8, long* __restrict__ CBf8,
        float* __restrict__ norms, double* __restrict__ lsum) {
  const int bb = blockIdx.x;
  const int tid = threadIdx.x;
  if (bb < 512) {  // ---- X convert: coalesced read -> LDS transpose -> coalesced write
    __shared__ long xl[4096 + 256];   // padded: upad = unit + (unit>>4)
    __shared__ float sp[8];
    float s = 0.f;
#pragma unroll
    for (int c = 0; c < 8; ++c) {
      const int j = c * NT + tid;            // wave reads one full 2KB row
      const int r = j >> 6;
      const int d0 = (j & 63) * 8;
      const float* src = X + ((size_t)bb * BM + r) * DIM + d0;
      const float4 a = *(const float4*)src;
      const float4 cc = *(const float4*)(src + 4);
      s += a.x * a.x + a.y * a.y + a.z * a.z + a.w * a.w +
           cc.x * cc.x + cc.y * cc.y + cc.z * cc.z + cc.w * cc.w;
      const int dk = d0 >> 6, ks = (d0 >> 5) & 1, l4 = (d0 >> 3) & 3;
      const int wn = (r >> 5) & 1, nf = (r >> 4) & 1, l15 = r & 15;
      const int unit = dk * 512 + wn * 256 + nf * 128 + ks * 64 + l4 * 16 + l15;
      const int2 v = pk8_fp8(a, cc);
      *(int2*)&xl[unit + (unit >> 4)] = v;
    }
    __syncthreads();
    long* dst = Xf8 + (size_t)bb * 4096;
#pragma unroll
    for (int k = 0; k < 8; ++k) {
      const int u = k * NT + tid;
      dst[u] = xl[u + (u >> 4)];
    }
#pragma unroll
    for (int m = 1; m < 64; m <<= 1) s += __shfl_xor(s, m, 64);
    const int lane = tid & 63, w = tid >> 6;
    if (lane == 0) sp[w] = s;
    __syncthreads();
    if (tid == 0) {
      double t = 0.0;
      for (int i = 0; i < 8; ++i) t += (double)sp[i];
      atomicAdd(&lsum[bb & 63], t);
    }
  } else if (bb < 640) {  // ---- CB convert: swizzled tile unit (ct,dk)
    const int id = (bb - 512) * NT + tid;  // 0 .. 65535
    const int ct = id >> 14;
    const int dk = (id >> 11) & 7;
    const int u = id & 2047;
    const int r = u >> 3, qp = u & 7;
    const int q = (qp + 8 - ((r >> 1) & 7)) & 7;
    const float* src = CB + ((size_t)ct * BN + r) * DIM + dk * BK + q * 8;
    const float4 a = *(const float4*)src;
    const float4 c = *(const float4*)(src + 4);
    *(int2*)(CBf8 + id) = pk8_fp8(a, c);
  } else {  // ---- norms (f32 exact): one wave per code
    const int gw = (bb - 640) * 8 + (tid >> 6);
    const int l = tid & 63;
    const float4 a = *(const float4*)&CB[(size_t)gw * DIM + l * 8];
    const float4 b = *(const float4*)&CB[(size_t)gw * DIM + l * 8 + 4];
    float s = a.x * a.x + a.y * a.y + a.z * a.z + a.w * a.w +
              b.x * b.x + b.y * b.y + b.z * b.z + b.w * b.w;
#pragma unroll
    for (int m = 1; m < 64; m <<= 1) s += __shfl_xor(s, m, 64);
    if (l == 0) norms[gw] = s;
  }
}

// ------- main: fp8 MFMA, 2-dk merged phases, additive swizzle, X frags from global -------
__global__ void __launch_bounds__(NT, 4)
vq_main10(const long* __restrict__ Xf8, const long* __restrict__ CBf8,
          const float* __restrict__ CB, const float* __restrict__ norms,
          float* __restrict__ outq, double* __restrict__ lsum) {
  __shared__ long Cs[2][2 * CUNITS];  // 32 KB x2
  __shared__ float snorm[KCODES];     // 4 KB
  __shared__ float redm[BM][4];
  __shared__ int redi[BM][4];
  __shared__ int idxs[BM];
  __shared__ float wpart[8];

  const int tid = threadIdx.x;
  const int lane = tid & 63;
  const int l15 = lane & 15;
  const int l4 = lane >> 4;
  const int wid = tid >> 6;
  const int wm = wid & 3;        // code group (64 codes)
  const int wn = wid >> 2;       // row group (32 rows)
  const int b = blockIdx.x;
  const int row0 = b * BM;

  for (int i = tid; i < KCODES; i += NT) snorm[i] = norms[i];

  // per-wave X fragment base (fragment-linear; one coalesced 8B/lane load per frag)
  const long* xw = Xf8 + (size_t)b * 4096 + wn * 256 + lane;

  auto stage = [&](int bf, int tt) {   // 4 gload_lds (16B) -> 32 KB dk-pair tile
    const int ct = tt >> 2, pr = tt & 3;
    const char* cp = (const char*)(CBf8 + (size_t)(ct * NDK + pr * 2) * CUNITS);
    char* dst = (char*)&Cs[bf][0];
#pragma unroll
    for (int k = 0; k < 4; ++k) {
      const int o = (tid + k * NT) * 16;
      GLOAD_LDS(cp + o, dst + o);
    }
  };

  f32x4 acc[4][2];                 // [mf codes][nf rows]
  float rmin[2]; int ridx[2];
#pragma unroll
  for (int i = 0; i < 2; ++i) { rmin[i] = FLT_MAX; ridx[i] = 0; }

  stage(0, 0);
  __syncthreads();

  for (int tt = 0; tt < NPH; ++tt) {
    const int pr = tt & 3;
    const int cur = tt & 1;
    // X fragments for both dk of this pair (older in vmcnt order than the stage)
    long bfr[2][2][2];   // [dkp][ks][nf]
#pragma unroll
    for (int dkp = 0; dkp < 2; ++dkp) {
      const long* xp = xw + (pr * 2 + dkp) * 512;
#pragma unroll
      for (int ks = 0; ks < 2; ++ks)
#pragma unroll
        for (int nf = 0; nf < 2; ++nf)
          bfr[dkp][ks][nf] = xp[nf * 128 + ks * 64];
    }
    if (tt + 1 < NPH) stage(cur ^ 1, tt + 1);   // prefetch spans the MFMA phase

    if (pr == 0) {
      const f32x4 z = {0.f, 0.f, 0.f, 0.f};
#pragma unroll
      for (int mf = 0; mf < 4; ++mf)
#pragma unroll
        for (int nf = 0; nf < 2; ++nf) acc[mf][nf] = z;
    }
#pragma unroll
    for (int dkp = 0; dkp < 2; ++dkp) {
#pragma unroll
      for (int ks = 0; ks < 2; ++ks) {
        long af[4];
#pragma unroll
        for (int mf = 0; mf < 4; ++mf) {
          const int r = wm * 64 + mf * 16 + l15;
          const int ph = ((ks * 4 + l4) + (l15 >> 1)) & 7;  // additive swizzle
          af[mf] = Cs[cur][dkp * CUNITS + r * 8 + ph];
        }
        __builtin_amdgcn_s_setprio(1);
#pragma unroll
        for (int mf = 0; mf < 4; ++mf)
#pragma unroll
          for (int nf = 0; nf < 2; ++nf)
            acc[mf][nf] = __builtin_amdgcn_mfma_f32_16x16x32_fp8_fp8(
                af[mf], bfr[dkp][ks][nf], acc[mf][nf], 0, 0, 0);
        __builtin_amdgcn_s_setprio(0);
      }
    }
    if (pr == 3) {  // fold finished code-tile into running argmin
      const int ct = tt >> 2;
#pragma unroll
      for (int mf = 0; mf < 4; ++mf) {
#pragma unroll
        for (int r = 0; r < 4; ++r) {
          const int code = ct * BN + wm * 64 + mf * 16 + l4 * 4 + r;
          const float cn = snorm[code];
#pragma unroll
          for (int nf = 0; nf < 2; ++nf) {
            const float s = fmaf(-2.f, acc[mf][nf][r], cn);
            if (s < rmin[nf]) { rmin[nf] = s; ridx[nf] = code; }
          }
        }
      }
    }
    __syncthreads();   // buffer swap; co-resident block hides the drain
  }

  // cross-lane argmin (lanes l15, +16, +32, +48 share a row; tie -> lowest idx)
#pragma unroll
  for (int m = 16; m <= 32; m <<= 1) {
#pragma unroll
    for (int nf = 0; nf < 2; ++nf) {
      const float om = __shfl_xor(rmin[nf], m, 64);
      const int oi = __shfl_xor(ridx[nf], m, 64);
      if (om < rmin[nf] || (om == rmin[nf] && oi < ridx[nf])) {
        rmin[nf] = om; ridx[nf] = oi;
      }
    }
  }
  if (l4 == 0) {
#pragma unroll
    for (int nf = 0; nf < 2; ++nf) {
      const int row = wn * 32 + nf * 16 + l15;
      redm[row][wm] = rmin[nf];
      redi[row][wm] = ridx[nf];
    }
  }
  __syncthreads();

  float tot = 0.f;
  if (tid < BM) {   // cross-wave reduce (4 code-group waves per row)
    float bm = redm[tid][0]; int bi = redi[tid][0];
#pragma unroll
    for (int c = 1; c < 4; ++c) {
      const float m_ = redm[tid][c]; const int i_ = redi[tid][c];
      if (m_ < bm || (m_ == bm && i_ < bi)) { bm = m_; bi = i_; }
    }
    idxs[tid] = bi;
    tot = bm;       // min(||c||^2 - 2 x.c); sum(x^2) added by prep pass
  }
#pragma unroll
  for (int m = 1; m < 64; m <<= 1) tot += __shfl_xor(tot, m, 64);
  if (lane == 0) wpart[wid] = tot;
  __syncthreads();
  if (tid == 0) {
    double s = 0.0;
    for (int i = 0; i < 8; ++i) s += (double)wpart[i];
    atomicAdd(&lsum[blockIdx.x & 63], s);
  }

  // gather + write quantized (exact f32 codebook rows, CB is L2-hot)
  for (int g = tid; g < BM * (DIM / 4); g += NT) {
    const int row = g >> 7;
    const int d4 = (g & 127) * 4;
    const int idx = idxs[row];
    *(float4*)&outq[(size_t)(row0 + row) * DIM + d4] =
        *(const float4*)&CB[(size_t)idx * DIM + d4];
  }
}

// ------------- fallback (round-2 path, small workspace; own constants) -------------
constexpr int FBM = 128, FBN = 256, FBK = 64, FNT = 512, FNDK = 8, FTT = 32;

__global__ void __launch_bounds__(FNT, 2)
vq_main_fb(const float* __restrict__ X, const float* __restrict__ CB,
           const float* __restrict__ norms, float* __restrict__ outq,
           double* __restrict__ lsum) {
  __shared__ u16 Xs[2][FBM * FBK];
  __shared__ u16 Cs[2][FBN * FBK];
  __shared__ float snorm[KCODES];
  __shared__ float redm[FBM][4];
  __shared__ int redi[FBM][4];
  __shared__ int idxs[FBM];
  __shared__ float wpart[8];

  const int tid = threadIdx.x;
  const int lane = tid & 63;
  const int l15 = lane & 15;
  const int l4 = lane >> 4;
  const int wid = tid >> 6;
  const int wm = wid & 3;
  const int wn = wid >> 2;
  const int row0 = blockIdx.x * FBM;

  for (int i = tid; i < KCODES; i += FNT) snorm[i] = norms[i];

  int xlds[2]; const float* xbase[2];
#pragma unroll
  for (int k = 0; k < 2; ++k) {
    const int u = tid + k * FNT;
    const int r = u >> 3, q = u & 7, ph = q ^ (r & 7);
    xlds[k] = r * FBK + ph * 8;
    xbase[k] = X + (size_t)(row0 + r) * DIM + q * 8;
  }
  int clds[4]; const float* cbase[4];
#pragma unroll
  for (int k = 0; k < 4; ++k) {
    const int u = tid + k * FNT;
    const int r = u >> 3, q = u & 7, ph = q ^ (r & 7);
    clds[k] = r * FBK + ph * 8;
    cbase[k] = CB + (size_t)r * DIM + q * 8;
  }

  f32x4 acc[4][4];
  float rmin[4]; int ridx[4];
#pragma unroll
  for (int i = 0; i < 4; ++i) { rmin[i] = FLT_MAX; ridx[i] = 0; }
  float sq = 0.f;

  float4 lx[2][2], lc[4][2];
  auto load_tile = [&](int tn) {
    const int ct = tn >> 3, dk = tn & 7;
    const int xo = dk * FBK;
    const size_t co = (size_t)ct * FBN * DIM + dk * FBK;
#pragma unroll
    for (int k = 0; k < 2; ++k) {
      lx[k][0] = *(const float4*)(xbase[k] + xo);
      lx[k][1] = *(const float4*)(xbase[k] + xo + 4);
    }
#pragma unroll
    for (int k = 0; k < 4; ++k) {
      lc[k][0] = *(const float4*)(cbase[k] + co);
      lc[k][1] = *(const float4*)(cbase[k] + co + 4);
    }
  };
  auto write_tile = [&](int bb, bool acc_sq) {
#pragma unroll
    for (int k = 0; k < 2; ++k) {
      u16x8 v;
      const float* f = (const float*)&lx[k][0];
#pragma unroll
      for (int j = 0; j < 8; ++j) {
        const float x = f[j];
        if (acc_sq) sq = fmaf(x, x, sq);
        v[j] = f2bf(x);
      }
      *(u16x8*)&Xs[bb][xlds[k]] = v;
    }
#pragma unroll
    for (int k = 0; k < 4; ++k) {
      u16x8 v;
      const float* f = (const float*)&lc[k][0];
#pragma unroll
      for (int j = 0; j < 8; ++j) v[j] = f2bf(f[j]);
      *(u16x8*)&Cs[bb][clds[k]] = v;
    }
  };

  load_tile(0);
  write_tile(0, true);
  __syncthreads();

  int cur = 0;
  for (int t = 0; t < FTT; ++t) {
    const int dk = t & 7;
    const bool pre = (t + 1 < FTT);
    if (pre) load_tile(t + 1);
    if (dk == 0) {
      const f32x4 z = {0.f, 0.f, 0.f, 0.f};
#pragma unroll
      for (int mf = 0; mf < 4; ++mf)
#pragma unroll
        for (int nf = 0; nf < 4; ++nf) acc[mf][nf] = z;
    }
    const u16* xb = Xs[cur];
    const u16* cb = Cs[cur];
#pragma unroll
    for (int ks = 0; ks < 2; ++ks) {
      bf16x8 af[4], bfr[4];
#pragma unroll
      for (int mf = 0; mf < 4; ++mf) {
        const int r = wm * 64 + mf * 16 + l15;
        const int ph = (ks * 4 + l4) ^ (r & 7);
        af[mf] = *(const bf16x8*)&cb[r * FBK + ph * 8];
      }
#pragma unroll
      for (int nf = 0; nf < 4; ++nf) {
        const int r = wn * 64 + nf * 16 + l15;
        const int ph = (ks * 4 + l4) ^ (r & 7);
        bfr[nf] = *(const bf16x8*)&xb[r * FBK + ph * 8];
      }
#pragma unroll
      for (int mf = 0; mf < 4; ++mf)
#pragma unroll
        for (int nf = 0; nf < 4; ++nf)
          acc[mf][nf] = __builtin_amdgcn_mfma_f32_16x16x32_bf16(
              af[mf], bfr[nf], acc[mf][nf], 0, 0, 0);
    }
    if (dk == FNDK - 1) {
      const int ct = t >> 3;
#pragma unroll
      for (int mf = 0; mf < 4; ++mf) {
#pragma unroll
        for (int r = 0; r < 4; ++r) {
          const int code = ct * FBN + wm * 64 + mf * 16 + l4 * 4 + r;
          const float cn = snorm[code];
#pragma unroll
          for (int nf = 0; nf < 4; ++nf) {
            const float s = fmaf(-2.f, acc[mf][nf][r], cn);
            if (s < rmin[nf]) { rmin[nf] = s; ridx[nf] = code; }
          }
        }
      }
    }
    if (pre) write_tile(cur ^ 1, (t + 1) < FNDK);
    __syncthreads();
    cur ^= 1;
  }

#pragma unroll
  for (int m = 16; m <= 32; m <<= 1) {
#pragma unroll
    for (int nf = 0; nf < 4; ++nf) {
      const float om = __shfl_xor(rmin[nf], m, 64);
      const int oi = __shfl_xor(ridx[nf], m, 64);
      if (om < rmin[nf] || (om == rmin[nf] && oi < ridx[nf])) {
        rmin[nf] = om; ridx[nf] = oi;
      }
    }
  }
  if (l4 == 0) {
#pragma unroll
    for (int nf = 0; nf < 4; ++nf) {
      const int row = wn * 64 + nf * 16 + l15;
      redm[row][wm] = rmin[nf];
      redi[row][wm] = ridx[nf];
    }
  }
  __syncthreads();

  float tot = sq;
  if (tid < FBM) {
    float bm = redm[tid][0]; int bi = redi[tid][0];
#pragma unroll
    for (int c = 1; c < 4; ++c) {
      const float m_ = redm[tid][c]; const int i_ = redi[tid][c];
      if (m_ < bm || (m_ == bm && i_ < bi)) { bm = m_; bi = i_; }
    }
    idxs[tid] = bi;
    tot += bm;
  }
#pragma unroll
  for (int m = 1; m < 64; m <<= 1) tot += __shfl_xor(tot, m, 64);
  if (lane == 0) wpart[wid] = tot;
  __syncthreads();
  if (tid == 0) {
    double s = 0.0;
    for (int i = 0; i < 8; ++i) s += (double)wpart[i];
    atomicAdd(&lsum[blockIdx.x & 63], s);
  }

  for (int g = tid; g < FBM * (DIM / 4); g += FNT) {
    const int row = g >> 7;
    const int d4 = (g & 127) * 4;
    const int idx = idxs[row];
    *(float4*)&outq[(size_t)(row0 + row) * DIM + d4] =
        *(const float4*)&CB[(size_t)idx * DIM + d4];
  }
}

__global__ void vq_norms_kernel(const float* __restrict__ cb,
                                float* __restrict__ norms) {
  const int gw = (int)((blockIdx.x * blockDim.x + threadIdx.x) >> 6);
  const int l = threadIdx.x & 63;
  const float4 a = *(const float4*)&cb[(size_t)gw * DIM + l * 8];
  const float4 b = *(const float4*)&cb[(size_t)gw * DIM + l * 8 + 4];
  float s = a.x * a.x + a.y * a.y + a.z * a.z + a.w * a.w +
            b.x * b.x + b.y * b.y + b.z * b.z + b.w * b.w;
#pragma unroll
  for (int m = 1; m < 64; m <<= 1) s += __shfl_xor(s, m, 64);
  if (l == 0) norms[gw] = s;
}

__global__ void vq_finalize_kernel(const double* __restrict__ lsum,
                                   float* __restrict__ out) {
  double t = 0.0;
  for (int i = 0; i < 64; ++i) t += lsum[i];
  out[0] = (float)(1.25 * t / (double)((size_t)LAT_ROWS * DIM));
}

extern "C" void kernel_launch(void* const* d_in, const int* in_sizes, int n_in,
                              void* d_out, int out_size, void* d_ws, size_t ws_size,
                              hipStream_t stream) {
  const float* X = (const float*)d_in[0];     // [32768, 512] f32
  const float* CB = (const float*)d_in[1];    // [1024, 512] f32
  float* out = (float*)d_out;                 // quantized [16777216] + loss [1]
  double* lsum = (double*)((char*)d_ws + WS_LSUM);   // 64 doubles
  float* norms = (float*)((char*)d_ws + WS_NORM);    // 1024 f32

  hipMemsetAsync(d_ws, 0, 512, stream);
  if (ws_size >= WS_NEEDED) {
    long* CBf8 = (long*)((char*)d_ws + WS_CBF8);
    long* Xf8 = (long*)((char*)d_ws + WS_XF8);
    vq_prep<<<768, NT, 0, stream>>>(X, CB, Xf8, CBf8, norms, lsum);
    vq_main10<<<LAT_ROWS / BM, NT, 0, stream>>>(Xf8, CBf8, CB, norms, out, lsum);
  } else {
    vq_norms_kernel<<<KCODES / 4, 256, 0, stream>>>(CB, norms);
    vq_main_fb<<<LAT_ROWS / FBM, FNT, 0, stream>>>(X, CB, norms, out, lsum);
  }
  vq_finalize_kernel<<<1, 1, 0, stream>>>(lsum, out + (size_t)LAT_ROWS * DIM);
}